// Round 3
// baseline (59.134 us; speedup 1.0000x reference)
//
#include <hip/hip_runtime.h>
#include <hip/hip_bf16.h>

// Problem: B=16, C=256, H=64, W=64, OUT=256
//   scale[b,c] = mean(context[b,c,:,:])
//   out[b,o,hw] = sum_c w1[o,c]*scale[b,c]*x[b,c,hw] + b1[o]
// Strategy: fold scale into w1 -> per-batch bf16 GEMM via MFMA.
// R3: fix R2's out-of-range LDS swizzle (mask 16/24 spilled into next row ->
//     collisions + unwritten slots -> NaN). Swizzle now 1 bit: s(k)=((k>>3)&1)<<3.
//     Reads: 16 banks, 2 addrs/bank (2-way, free). Bijective per row.

typedef __attribute__((ext_vector_type(8))) short short8;
typedef __attribute__((ext_vector_type(4))) float f32x4;
typedef __attribute__((ext_vector_type(4))) unsigned int u32x4;

static __device__ __forceinline__ unsigned short f2bf(float f) {
    unsigned int u = __float_as_uint(f);
    unsigned int r = u + 0x7FFFu + ((u >> 16) & 1u);  // round-to-nearest-even
    return (unsigned short)(r >> 16);
}

static __device__ __forceinline__ unsigned int perm_b32(unsigned int a, unsigned int b,
                                                        unsigned int sel, int half) {
#if __has_builtin(__builtin_amdgcn_perm)
    (void)half;
    return __builtin_amdgcn_perm(a, b, sel);  // combined {b:bytes0-3, a:bytes4-7}
#else
    return half ? ((a & 0xffff0000u) | (b >> 16)) : ((a << 16) | (b & 0xffffu));
#endif
}

// ---------------- Kernel 1: scale[b*256+c] = mean over 4096 elems ----------
__global__ __launch_bounds__(256) void scale_kernel(const float* __restrict__ ctx,
                                                    float* __restrict__ scale) {
    const int bc = blockIdx.x;              // 0..4095
    const float4* p = (const float4*)(ctx + (size_t)bc * 4096);
    const int t = threadIdx.x;
    float s = 0.f;
#pragma unroll
    for (int k = 0; k < 4; k++) {
        float4 v = p[t + k * 256];
        s += v.x + v.y + v.z + v.w;
    }
#pragma unroll
    for (int off = 32; off > 0; off >>= 1) s += __shfl_down(s, off);
    __shared__ float ws[4];
    if ((t & 63) == 0) ws[t >> 6] = s;
    __syncthreads();
    if (t == 0) scale[bc] = (ws[0] + ws[1] + ws[2] + ws[3]) * (1.0f / 4096.0f);
}

// ---------------- Kernel 2: w2[b][o][c] = bf16(w1[o][c] * scale[b][c]) -----
__global__ __launch_bounds__(256) void w2_kernel(const float* __restrict__ w1,
                                                 const float* __restrict__ scale,
                                                 unsigned short* __restrict__ w2) {
    const int idx = blockIdx.x * 256 + threadIdx.x;
    const int c4 = idx * 4;
    const int b = c4 >> 16;
    const int oc = c4 & 65535;
    const int c = oc & 255;
    float4 w = *(const float4*)(w1 + oc);
    float4 sc = *(const float4*)(scale + b * 256 + c);
    ushort4 r;
    r.x = f2bf(w.x * sc.x);
    r.y = f2bf(w.y * sc.y);
    r.z = f2bf(w.z * sc.z);
    r.w = f2bf(w.w * sc.w);
    *(ushort4*)(w2 + (size_t)b * 65536 + oc) = r;
}

// ---------------- Kernel 3: per-batch GEMM out = w2[b](256x256) * x[b](256x4096) + b1
// 2048 blocks (16 batches x 128 col-tiles of 32), 256 threads = 4 waves.
// Wave w computes rows [64w, 64w+64) x 32 cols. x tile staged in LDS as bf16.
// LDS (dword units): dw = k*16 + (cd ^ s(k)),  cd = c>>1 in [0,16),
//   s(k) = ((k>>3)&1)<<3  -- in-range (<=15), bijective per row.
// Fragment read (k = ks*32+g*8+e): (k>>3)&1 == g&1 -> per-thread-constant XOR.
__global__ __launch_bounds__(256, 6) void gemm_kernel(const float* __restrict__ x,
                                                      const unsigned short* __restrict__ w2,
                                                      const float* __restrict__ b1,
                                                      float* __restrict__ out) {
    __shared__ unsigned int xl[4096];  // 256 x 32 bf16, swizzled, 16 KiB

    const int bid = blockIdx.x;
    const int b = bid >> 7;           // batch
    const int hw0 = (bid & 127) * 32; // column tile base
    const int tid = threadIdx.x;
    const int w = tid >> 6;
    const int lane = tid & 63;
    const int g = lane >> 4;          // 0..3
    const int lr = lane & 15;         // 0..15
    const int o0 = w * 64;

    const unsigned short* Aw = w2 + (size_t)b * 65536;  // [256][256] bf16
    const float* Xb = x + (size_t)b * (256 * 4096);

    // ---- stage x tile: 8 float4/thread, coalesced; cvt bf16; swizzled b64 writes
#pragma unroll
    for (int i = 0; i < 8; i++) {
        const int flat = i * 256 + tid;   // 0..2047
        const int k = flat >> 3;          // 0..255
        const int cd = (flat & 7) * 2;    // dword column 0,2,..,14 (even)
        float4 v = *(const float4*)(Xb + (size_t)k * 4096 + hw0 + cd * 2);
        unsigned int lo = (unsigned int)f2bf(v.x) | ((unsigned int)f2bf(v.y) << 16);
        unsigned int hi = (unsigned int)f2bf(v.z) | ((unsigned int)f2bf(v.w) << 16);
        const int dw = k * 16 + (cd ^ (((k >> 3) & 1) << 3));  // even, 8B-aligned
        *(uint2*)&xl[dw] = make_uint2(lo, hi);
    }
    __syncthreads();

    f32x4 acc[4][2];
#pragma unroll
    for (int m = 0; m < 4; m++)
#pragma unroll
        for (int n = 0; n < 2; n++) acc[m][n] = (f32x4)(0.f);

    // per-thread fragment-read constants
    const int half = lr & 1;
    const unsigned int sel = half ? 0x07060302u : 0x05040100u;
    int csw[2];
#pragma unroll
    for (int nt = 0; nt < 2; nt++)
        csw[nt] = ((nt * 16 + lr) >> 1) ^ ((g & 1) << 3);

#pragma unroll
    for (int ks = 0; ks < 8; ks++) {
        short8 a[4];
#pragma unroll
        for (int m = 0; m < 4; m++)
            a[m] = *(const short8*)(Aw + (o0 + m * 16 + lr) * 256 + ks * 32 + g * 8);

#pragma unroll
        for (int nt = 0; nt < 2; nt++) {
            const int dwb = (ks * 32 + g * 8) * 16 + csw[nt];
            unsigned int d[8];
#pragma unroll
            for (int e = 0; e < 8; e++) d[e] = xl[dwb + e * 16];
            u32x4 pv;
#pragma unroll
            for (int j = 0; j < 4; j++) pv[j] = perm_b32(d[2 * j + 1], d[2 * j], sel, half);
            short8 bf = __builtin_bit_cast(short8, pv);
#pragma unroll
            for (int m = 0; m < 4; m++)
                acc[m][nt] = __builtin_amdgcn_mfma_f32_16x16x32_bf16(a[m], bf, acc[m][nt], 0, 0, 0);
        }
    }

    // ---- epilogue: D col = lane&15, row = 4*(lane>>4)+reg
    float* outb = out + (size_t)b * 256 * 4096 + hw0;
#pragma unroll
    for (int m = 0; m < 4; m++) {
#pragma unroll
        for (int r = 0; r < 4; r++) {
            const int row = o0 + m * 16 + g * 4 + r;
            const float bias = b1[row];
#pragma unroll
            for (int nt = 0; nt < 2; nt++)
                outb[(size_t)row * 4096 + nt * 16 + lr] = acc[m][nt][r] + bias;
        }
    }
}

extern "C" void kernel_launch(void* const* d_in, const int* in_sizes, int n_in,
                              void* d_out, int out_size, void* d_ws, size_t ws_size,
                              hipStream_t stream) {
    const float* x = (const float*)d_in[0];
    const float* context = (const float*)d_in[1];
    const float* w1 = (const float*)d_in[2];
    const float* b1 = (const float*)d_in[3];
    float* out = (float*)d_out;

    float* scale = (float*)d_ws;
    unsigned short* w2 = (unsigned short*)((char*)d_ws + 16384);

    scale_kernel<<<4096, 256, 0, stream>>>(context, scale);
    w2_kernel<<<1024, 256, 0, stream>>>(w1, scale, w2);
    gemm_kernel<<<2048, 256, 0, stream>>>(x, w2, b1, out);
}